// Round 7
// baseline (162.578 us; speedup 1.0000x reference)
//
#include <hip/hip_runtime.h>

#define BB    4
#define TE    1024
#define TD    512
#define HH    128
#define DTILE 2
#define TTILE 32
#define C2    2.8853900817779268f   // 2*log2(e); proj pre-scales W_s and U_h by this
#define LOG2E 1.4426950408889634f

// Async global->LDS, 16B per lane. LDS dest = wave-uniform base + lane*16.
__device__ __forceinline__ void gload16_lds(const float* g, float* l) {
    __builtin_amdgcn_global_load_lds(
        (const __attribute__((address_space(1))) unsigned int*)g,
        (__attribute__((address_space(3))) unsigned int*)l, 16, 0, 0);
}

__device__ __forceinline__ float sigsum4(float4 wv, float4 cu, float4 v, float acc) {
    // acc += sum_i v_i * 1/(1 + 2^(wv_i + cu_i))   [inputs pre-scaled by C2]
    acc = fmaf(v.x, __builtin_amdgcn_rcpf(1.0f + __builtin_amdgcn_exp2f(wv.x + cu.x)), acc);
    acc = fmaf(v.y, __builtin_amdgcn_rcpf(1.0f + __builtin_amdgcn_exp2f(wv.y + cu.y)), acc);
    acc = fmaf(v.z, __builtin_amdgcn_rcpf(1.0f + __builtin_amdgcn_exp2f(wv.z + cu.z)), acc);
    acc = fmaf(v.w, __builtin_amdgcn_rcpf(1.0f + __builtin_amdgcn_exp2f(wv.w + cu.w)), acc);
    return acc;
}

// ---------------------------------------------------------------------------
// Kernel 1: tiled projections, output pre-scaled by C2 (unchanged).
// ---------------------------------------------------------------------------
__global__ __launch_bounds__(256) void proj_gemm(
    const float* __restrict__ enc, const float* __restrict__ dec,
    const float* __restrict__ Wa,  const float* __restrict__ Ua,
    float* __restrict__ out)
{
    __shared__ float Xs[64 * 33];
    __shared__ float Ws[32 * 64];

    const int tid = threadIdx.x;
    const int rt = blockIdx.x >> 1, ch = blockIdx.x & 1;
    const int r0 = rt * 64, c0 = ch * 64;

    const float* X; const float* W; int rX0;
    if (r0 < BB * TE) { X = enc; W = Wa; rX0 = r0; }
    else              { X = dec; W = Ua; rX0 = r0 - BB * TE; }

    const int c4 = tid & 15;
    const int rg = tid >> 4;

    float4 a0 = {0,0,0,0}, a1 = a0, a2 = a0, a3 = a0;

    for (int kc = 0; kc < 4; ++kc) {
        #pragma unroll
        for (int i = 0; i < 2; ++i) {
            int idx = tid + i * 256;
            int r  = idx >> 3, k4 = idx & 7;
            *(float4*)&Xs[r * 33 + k4 * 4] =
                *(const float4*)&X[(rX0 + r) * HH + kc * 32 + k4 * 4];
            int kk = idx >> 4, cc = idx & 15;
            *(float4*)&Ws[kk * 64 + cc * 4] =
                *(const float4*)&W[(kc * 32 + kk) * HH + c0 + cc * 4];
        }
        __syncthreads();
        #pragma unroll 8
        for (int k = 0; k < 32; ++k) {
            float4 wv = *(const float4*)&Ws[k * 64 + c4 * 4];
            float x0 = Xs[(rg * 4 + 0) * 33 + k];
            float x1 = Xs[(rg * 4 + 1) * 33 + k];
            float x2 = Xs[(rg * 4 + 2) * 33 + k];
            float x3 = Xs[(rg * 4 + 3) * 33 + k];
            a0.x = fmaf(x0, wv.x, a0.x); a0.y = fmaf(x0, wv.y, a0.y);
            a0.z = fmaf(x0, wv.z, a0.z); a0.w = fmaf(x0, wv.w, a0.w);
            a1.x = fmaf(x1, wv.x, a1.x); a1.y = fmaf(x1, wv.y, a1.y);
            a1.z = fmaf(x1, wv.z, a1.z); a1.w = fmaf(x1, wv.w, a1.w);
            a2.x = fmaf(x2, wv.x, a2.x); a2.y = fmaf(x2, wv.y, a2.y);
            a2.z = fmaf(x2, wv.z, a2.z); a2.w = fmaf(x2, wv.w, a2.w);
            a3.x = fmaf(x3, wv.x, a3.x); a3.y = fmaf(x3, wv.y, a3.y);
            a3.z = fmaf(x3, wv.z, a3.z); a3.w = fmaf(x3, wv.w, a3.w);
        }
        __syncthreads();
    }

    float4 accs[4] = {a0, a1, a2, a3};
    #pragma unroll
    for (int j = 0; j < 4; ++j) {
        float4 o = accs[j];
        o.x *= C2; o.y *= C2; o.z *= C2; o.w *= C2;
        *(float4*)&out[(r0 + rg * 4 + j) * HH + c0 + c4 * 4] = o;
    }
}

// ---------------------------------------------------------------------------
// Kernel 2: fused energies -> softmax -> context. DTILE=2 -> 1024 blocks =
// 4 blocks/CU; LDS 40 KB (32 KB tile dbuf + 8 KB e_s) -> 4 blocks resident
// -> 32 waves/CU (hw max). Barrier-free pipelined main loops as R5/R6.
// ---------------------------------------------------------------------------
__global__ __launch_bounds__(512, 8) void attn_fused(
    const float* __restrict__ enc,    // [B, TE, H] raw
    const float* __restrict__ ws,     // [B*TE, H]  = C2 * W_s
    const float* __restrict__ uh,     // [B*TD, H]  = C2 * U_h
    const float* __restrict__ Va,     // [H]
    float* __restrict__ c_out,        // [B, TD, H]
    float* __restrict__ e_out)        // [B, TD, TE]
{
    __shared__ float tile[8 * 1024];  // 8 waves x (2 bufs x 512 floats) = 32 KB
    __shared__ float e_s[DTILE * TE]; //  8 KB

    const int tid = threadIdx.x;
    const int l   = tid & 63;
    const int w   = tid >> 6;            // 0..7 (row-quad owner)
    const int b   = blockIdx.x >> 8;     // 256 blocks per batch
    const int d0  = (blockIdx.x & 255) * DTILE;

    const int c16 = l & 15;              // h-chunk selector / reduce dim
    const int r4  = l >> 4;              // row within quad

    float* slab = &tile[w * 1024];       // wave-private: buf p at slab + p*512

    // Register fragments straight from global (L2-resident)
    float4 cu4[DTILE][2], v4[2];
    #pragma unroll
    for (int j = 0; j < 2; ++j) {
        v4[j] = *(const float4*)&Va[(j * 16 + c16) * 4];
        #pragma unroll
        for (int d = 0; d < DTILE; ++d)
            cu4[d][j] = *(const float4*)&uh[((size_t)b * TD + d0 + d) * HH + (j * 16 + c16) * 4];
    }
    float Vsum = 0.f;
    #pragma unroll
    for (int j = 0; j < 2; ++j) Vsum += v4[j].x + v4[j].y + v4[j].z + v4[j].w;
    Vsum += __shfl_xor(Vsum, 1);
    Vsum += __shfl_xor(Vsum, 2);
    Vsum += __shfl_xor(Vsum, 4);
    Vsum += __shfl_xor(Vsum, 8);

    const float* ws_w  = ws  + (size_t)b * TE * HH + w * 4 * HH;
    const float* enc_w = enc + (size_t)b * TE * HH + w * 4 * HH;

    // ---------------- Phase 1: energies (pipelined, barrier-free) ----------
    auto p1c = [&](int tt, const float* buf) {
        float acc[DTILE] = {0.f, 0.f};
        #pragma unroll
        for (int j = 0; j < 2; ++j) {
            float4 wv = *(const float4*)&buf[r4 * HH + (j * 16 + c16) * 4];
            #pragma unroll
            for (int d = 0; d < DTILE; ++d)
                acc[d] = sigsum4(wv, cu4[d][j], v4[j], acc[d]);
        }
        #pragma unroll
        for (int d = 0; d < DTILE; ++d) {
            acc[d] += __shfl_xor(acc[d], 1);
            acc[d] += __shfl_xor(acc[d], 2);
            acc[d] += __shfl_xor(acc[d], 4);
            acc[d] += __shfl_xor(acc[d], 8);
        }
        if (c16 == 0) {
            #pragma unroll
            for (int d = 0; d < DTILE; ++d)
                e_s[d * TE + tt * TTILE + w * 4 + r4] = Vsum - 2.f * acc[d];
        }
    };

    #pragma unroll
    for (int i = 0; i < 2; ++i)                       // prologue: tile 0 -> buf0
        gload16_lds(ws_w + i * 256 + l * 4, slab + i * 256);

    for (int tt = 0; tt < TE / TTILE - 1; ++tt) {
        const float* src = ws_w + (size_t)(tt + 1) * TTILE * HH;
        float* nb = slab + ((tt + 1) & 1) * 512;
        #pragma unroll
        for (int i = 0; i < 2; ++i)
            gload16_lds(src + i * 256 + l * 4, nb + i * 256);
        __builtin_amdgcn_s_waitcnt(0x0F72);           // vmcnt(2): tile tt landed
        p1c(tt, slab + (tt & 1) * 512);
        __builtin_amdgcn_sched_barrier(0);            // pin DMA(tt+2) after reads(tt)
    }
    __builtin_amdgcn_s_waitcnt(0x0F70);               // vmcnt(0)
    p1c(TE / TTILE - 1, slab + ((TE / TTILE - 1) & 1) * 512);

    __syncthreads();   // all waves' raw energies visible

    // ---------------- Phase 2: softmax (d = w&1, four waves split quarters) --
    {
        const int d2 = w & 1, qf = w >> 1;    // qf in 0..3
        float ev[16];
        float m = -3.0e38f;
        #pragma unroll
        for (int i = 0; i < 16; ++i) {
            ev[i] = e_s[d2 * TE + i * 64 + l];
            m = fmaxf(m, ev[i]);
        }
        #pragma unroll
        for (int off = 32; off; off >>= 1) m = fmaxf(m, __shfl_xor(m, off));
        float s = 0.f;
        #pragma unroll
        for (int i = 0; i < 16; ++i) {
            ev[i] = __builtin_amdgcn_exp2f((ev[i] - m) * LOG2E);
            s += ev[i];
        }
        #pragma unroll
        for (int off = 32; off; off >>= 1) s += __shfl_xor(s, off);
        float inv = __builtin_amdgcn_rcpf(s);

        __syncthreads();   // all raw-energy reads done before overwrite
        float* eo = e_out + ((size_t)b * TD + d0 + d2) * TE;
        #pragma unroll
        for (int i = 0; i < 4; ++i) {
            int ii = qf * 4 + i;
            float p = ev[ii] * inv;
            e_s[d2 * TE + ii * 64 + l] = p;
            eo[ii * 64 + l] = p;
        }
        __syncthreads();   // normalized p visible to all waves
    }

    // ---------------- Phase 3: context (pipelined, barrier-free) ------------
    const int h4 = l & 31, tsub = l >> 5;
    float4 acc4[DTILE];
    #pragma unroll
    for (int d = 0; d < DTILE; ++d) acc4[d] = make_float4(0.f, 0.f, 0.f, 0.f);

    auto p3c = [&](int tt, const float* buf) {
        float2 ep[DTILE];
        #pragma unroll
        for (int d = 0; d < DTILE; ++d)
            ep[d] = *(const float2*)&e_s[d * TE + tt * TTILE + w * 4 + tsub * 2];
        #pragma unroll
        for (int k = 0; k < 2; ++k) {
            float4 x = *(const float4*)&buf[(tsub * 2 + k) * HH + h4 * 4];
            float p0 = k == 0 ? ep[0].x : ep[0].y;
            float p1 = k == 0 ? ep[1].x : ep[1].y;
            acc4[0].x = fmaf(p0, x.x, acc4[0].x); acc4[0].y = fmaf(p0, x.y, acc4[0].y);
            acc4[0].z = fmaf(p0, x.z, acc4[0].z); acc4[0].w = fmaf(p0, x.w, acc4[0].w);
            acc4[1].x = fmaf(p1, x.x, acc4[1].x); acc4[1].y = fmaf(p1, x.y, acc4[1].y);
            acc4[1].z = fmaf(p1, x.z, acc4[1].z); acc4[1].w = fmaf(p1, x.w, acc4[1].w);
        }
    };

    #pragma unroll
    for (int i = 0; i < 2; ++i)                       // prologue: tile 0 -> buf0
        gload16_lds(enc_w + i * 256 + l * 4, slab + i * 256);

    for (int tt = 0; tt < TE / TTILE - 1; ++tt) {
        const float* src = enc_w + (size_t)(tt + 1) * TTILE * HH;
        float* nb = slab + ((tt + 1) & 1) * 512;
        #pragma unroll
        for (int i = 0; i < 2; ++i)
            gload16_lds(src + i * 256 + l * 4, nb + i * 256);
        __builtin_amdgcn_s_waitcnt(0x0F72);           // vmcnt(2)
        p3c(tt, slab + (tt & 1) * 512);
        __builtin_amdgcn_sched_barrier(0);
    }
    __builtin_amdgcn_s_waitcnt(0x0F70);               // vmcnt(0)
    p3c(TE / TTILE - 1, slab + ((TE / TTILE - 1) & 1) * 512);

    // Combine tsub halves; park partials in tile (now dead); tree-reduce.
    #pragma unroll
    for (int d = 0; d < DTILE; ++d) {
        acc4[d].x += __shfl_xor(acc4[d].x, 32);
        acc4[d].y += __shfl_xor(acc4[d].y, 32);
        acc4[d].z += __shfl_xor(acc4[d].z, 32);
        acc4[d].w += __shfl_xor(acc4[d].w, 32);
    }
    __syncthreads();   // all waves done READING tile before we overwrite it
    float* c_red = tile;   // 8 waves x DTILE x HH = 8 KB <= 32 KB
    if (tsub == 0) {
        #pragma unroll
        for (int d = 0; d < DTILE; ++d)
            *(float4*)&c_red[(w * DTILE + d) * HH + h4 * 4] = acc4[d];
    }
    __syncthreads();

    if (w < DTILE && l < 32) {
        float4 o = make_float4(0.f, 0.f, 0.f, 0.f);
        #pragma unroll
        for (int ww = 0; ww < 8; ++ww) {
            float4 p = *(const float4*)&c_red[(ww * DTILE + w) * HH + l * 4];
            o.x += p.x; o.y += p.y; o.z += p.z; o.w += p.w;
        }
        *(float4*)&c_out[((size_t)b * TD + d0 + w) * HH + l * 4] = o;
    }
}

// ---------------------------------------------------------------------------
extern "C" void kernel_launch(void* const* d_in, const int* in_sizes, int n_in,
                              void* d_out, int out_size, void* d_ws, size_t ws_size,
                              hipStream_t stream) {
    (void)in_sizes; (void)n_in; (void)out_size; (void)ws_size;

    const float* enc = (const float*)d_in[0];
    const float* dec = (const float*)d_in[1];
    const float* Wa  = (const float*)d_in[2];
    const float* Ua  = (const float*)d_in[3];
    const float* Va  = (const float*)d_in[4];

    float* c_out = (float*)d_out;
    float* e_out = (float*)d_out + BB * TD * HH;

    float* proj = (float*)d_ws;
    float* ws_p = proj;                  // C2*W_s: [B*TE, H]
    float* uh_p = proj + BB * TE * HH;   // C2*U_h: [B*TD, H]

    proj_gemm<<<192, 256, 0, stream>>>(enc, dec, Wa, Ua, proj);
    attn_fused<<<(BB * TD) / DTILE, 512, 0, stream>>>(enc, ws_p, uh_p, Va, c_out, e_out);
}

// Round 8
// 137.732 us; speedup vs baseline: 1.1804x; 1.1804x over previous
//
#include <hip/hip_runtime.h>

#define BB    4
#define TE    1024
#define TD    512
#define HH    128
#define DTILE 4
#define TTILE 64
#define LOG2E 1.4426950408889634f

// Async global->LDS, 16B per lane. LDS dest = wave-uniform base + lane*16.
__device__ __forceinline__ void gload16_lds(const float* g, float* l) {
    __builtin_amdgcn_global_load_lds(
        (const __attribute__((address_space(1))) unsigned int*)g,
        (__attribute__((address_space(3))) unsigned int*)l, 16, 0, 0);
}

// tanh addition theorem: tanh(a+b) = (A+B)/(1+AB), A=tanh(a), B=tanh(b).
// acc += sum_i v_i * (A_i+B_i) * rcp(1 + A_i*B_i)   — 4 full-rate + 1 trans.
__device__ __forceinline__ float tanhsum4(float4 A, float4 B, float4 v, float acc) {
    acc = fmaf(v.x * (A.x + B.x), __builtin_amdgcn_rcpf(fmaf(A.x, B.x, 1.0f)), acc);
    acc = fmaf(v.y * (A.y + B.y), __builtin_amdgcn_rcpf(fmaf(A.y, B.y, 1.0f)), acc);
    acc = fmaf(v.z * (A.z + B.z), __builtin_amdgcn_rcpf(fmaf(A.z, B.z, 1.0f)), acc);
    acc = fmaf(v.w * (A.w + B.w), __builtin_amdgcn_rcpf(fmaf(A.w, B.w, 1.0f)), acc);
    return acc;
}

// Accurate-enough tanh for the proj epilogue (786K elems, off the hot path).
__device__ __forceinline__ float tanh_eval(float x) {
    float e = __builtin_amdgcn_exp2f(2.0f * LOG2E * x);
    return 1.0f - 2.0f * __builtin_amdgcn_rcpf(e + 1.0f);
}

// ---------------------------------------------------------------------------
// Kernel 1: tiled projections; epilogue applies tanh (A = tanh(enc@W),
// B = tanh(dec@U)) so the energy kernel can use the addition theorem.
// ---------------------------------------------------------------------------
__global__ __launch_bounds__(256) void proj_gemm(
    const float* __restrict__ enc, const float* __restrict__ dec,
    const float* __restrict__ Wa,  const float* __restrict__ Ua,
    float* __restrict__ out)
{
    __shared__ float Xs[64 * 33];
    __shared__ float Ws[32 * 64];

    const int tid = threadIdx.x;
    const int rt = blockIdx.x >> 1, ch = blockIdx.x & 1;
    const int r0 = rt * 64, c0 = ch * 64;

    const float* X; const float* W; int rX0;
    if (r0 < BB * TE) { X = enc; W = Wa; rX0 = r0; }
    else              { X = dec; W = Ua; rX0 = r0 - BB * TE; }

    const int c4 = tid & 15;
    const int rg = tid >> 4;

    float4 a0 = {0,0,0,0}, a1 = a0, a2 = a0, a3 = a0;

    for (int kc = 0; kc < 4; ++kc) {
        #pragma unroll
        for (int i = 0; i < 2; ++i) {
            int idx = tid + i * 256;
            int r  = idx >> 3, k4 = idx & 7;
            *(float4*)&Xs[r * 33 + k4 * 4] =
                *(const float4*)&X[(rX0 + r) * HH + kc * 32 + k4 * 4];
            int kk = idx >> 4, cc = idx & 15;
            *(float4*)&Ws[kk * 64 + cc * 4] =
                *(const float4*)&W[(kc * 32 + kk) * HH + c0 + cc * 4];
        }
        __syncthreads();
        #pragma unroll 8
        for (int k = 0; k < 32; ++k) {
            float4 wv = *(const float4*)&Ws[k * 64 + c4 * 4];
            float x0 = Xs[(rg * 4 + 0) * 33 + k];
            float x1 = Xs[(rg * 4 + 1) * 33 + k];
            float x2 = Xs[(rg * 4 + 2) * 33 + k];
            float x3 = Xs[(rg * 4 + 3) * 33 + k];
            a0.x = fmaf(x0, wv.x, a0.x); a0.y = fmaf(x0, wv.y, a0.y);
            a0.z = fmaf(x0, wv.z, a0.z); a0.w = fmaf(x0, wv.w, a0.w);
            a1.x = fmaf(x1, wv.x, a1.x); a1.y = fmaf(x1, wv.y, a1.y);
            a1.z = fmaf(x1, wv.z, a1.z); a1.w = fmaf(x1, wv.w, a1.w);
            a2.x = fmaf(x2, wv.x, a2.x); a2.y = fmaf(x2, wv.y, a2.y);
            a2.z = fmaf(x2, wv.z, a2.z); a2.w = fmaf(x2, wv.w, a2.w);
            a3.x = fmaf(x3, wv.x, a3.x); a3.y = fmaf(x3, wv.y, a3.y);
            a3.z = fmaf(x3, wv.z, a3.z); a3.w = fmaf(x3, wv.w, a3.w);
        }
        __syncthreads();
    }

    float4 accs[4] = {a0, a1, a2, a3};
    #pragma unroll
    for (int j = 0; j < 4; ++j) {
        float4 o = accs[j];
        o.x = tanh_eval(o.x); o.y = tanh_eval(o.y);
        o.z = tanh_eval(o.z); o.w = tanh_eval(o.w);
        *(float4*)&out[(r0 + rg * 4 + j) * HH + c0 + c4 * 4] = o;
    }
}

// ---------------------------------------------------------------------------
// Kernel 2: fused energies -> softmax -> context. R5 structure (best): 512
// blocks x 8 waves, wave-private double-buffered 8-row slabs, barrier-free
// pipelined loops (vmcnt(4)), energies via tanh addition theorem.
// ---------------------------------------------------------------------------
__global__ __launch_bounds__(512, 4) void attn_fused(
    const float* __restrict__ enc,    // [B, TE, H] raw
    const float* __restrict__ ta,     // [B*TE, H]  = tanh(W_s)
    const float* __restrict__ tb,     // [B*TD, H]  = tanh(U_h)
    const float* __restrict__ Va,     // [H]
    float* __restrict__ c_out,        // [B, TD, H]
    float* __restrict__ e_out)        // [B, TD, TE]
{
    __shared__ float tile[8 * 2048];  // 8 waves x (2 bufs x 1024 floats) = 64 KB
    __shared__ float e_s[DTILE * TE]; // 16 KB

    const int tid = threadIdx.x;
    const int l   = tid & 63;
    const int w   = tid >> 6;            // 0..7 (row-octet owner)
    const int b   = blockIdx.x >> 7;
    const int d0  = (blockIdx.x & 127) * DTILE;

    const int c8 = l & 7;                // h-chunk selector / reduce dim
    const int r8 = l >> 3;               // row within octet

    float* slab = &tile[w * 2048];       // wave-private: buf p at slab + p*1024

    // Register fragments straight from global (L2-resident)
    float4 B4[DTILE][4], v4[4];
    #pragma unroll
    for (int j = 0; j < 4; ++j) {
        v4[j] = *(const float4*)&Va[(j * 8 + c8) * 4];
        #pragma unroll
        for (int d = 0; d < DTILE; ++d)
            B4[d][j] = *(const float4*)&tb[((size_t)b * TD + d0 + d) * HH + (j * 8 + c8) * 4];
    }

    const float* ta_w  = ta  + (size_t)b * TE * HH + w * 8 * HH;
    const float* enc_w = enc + (size_t)b * TE * HH + w * 8 * HH;

    // ---------------- Phase 1: energies (pipelined, barrier-free) ----------
    auto p1c = [&](int tt, const float* buf) {
        float acc[DTILE] = {0.f, 0.f, 0.f, 0.f};
        #pragma unroll
        for (int j = 0; j < 4; ++j) {
            float4 A = *(const float4*)&buf[r8 * HH + (j * 8 + c8) * 4];
            #pragma unroll
            for (int d = 0; d < DTILE; ++d)
                acc[d] = tanhsum4(A, B4[d][j], v4[j], acc[d]);
        }
        #pragma unroll
        for (int d = 0; d < DTILE; ++d) {
            acc[d] += __shfl_xor(acc[d], 1);
            acc[d] += __shfl_xor(acc[d], 2);
            acc[d] += __shfl_xor(acc[d], 4);
        }
        if (c8 == 0) {
            #pragma unroll
            for (int d = 0; d < DTILE; ++d)
                e_s[d * TE + tt * TTILE + w * 8 + r8] = acc[d];
        }
    };

    #pragma unroll
    for (int i = 0; i < 4; ++i)                       // prologue: tile 0 -> buf0
        gload16_lds(ta_w + i * 256 + l * 4, slab + i * 256);

    for (int tt = 0; tt < 15; ++tt) {
        const float* src = ta_w + (size_t)(tt + 1) * TTILE * HH;
        float* nb = slab + ((tt + 1) & 1) * 1024;
        #pragma unroll
        for (int i = 0; i < 4; ++i)
            gload16_lds(src + i * 256 + l * 4, nb + i * 256);
        __builtin_amdgcn_s_waitcnt(0x0F74);           // vmcnt(4): tile tt landed
        p1c(tt, slab + (tt & 1) * 1024);
        __builtin_amdgcn_sched_barrier(0);            // pin DMA(tt+2) after reads(tt)
    }
    __builtin_amdgcn_s_waitcnt(0x0F70);               // vmcnt(0)
    p1c(15, slab + 1024);

    __syncthreads();   // all waves' raw energies visible

    // ---------------- Phase 2: softmax (d = w&3, two waves split halves) ----
    {
        const int d2 = w & 3, hf = w >> 2;
        float ev[16];
        float m = -3.0e38f;
        #pragma unroll
        for (int i = 0; i < 16; ++i) {
            ev[i] = e_s[d2 * TE + i * 64 + l];
            m = fmaxf(m, ev[i]);
        }
        #pragma unroll
        for (int off = 32; off; off >>= 1) m = fmaxf(m, __shfl_xor(m, off));
        float s = 0.f;
        #pragma unroll
        for (int i = 0; i < 16; ++i) {
            ev[i] = __builtin_amdgcn_exp2f((ev[i] - m) * LOG2E);
            s += ev[i];
        }
        #pragma unroll
        for (int off = 32; off; off >>= 1) s += __shfl_xor(s, off);
        float inv = __builtin_amdgcn_rcpf(s);

        __syncthreads();   // all raw-energy reads done before overwrite
        float* eo = e_out + ((size_t)b * TD + d0 + d2) * TE;
        #pragma unroll
        for (int i = 0; i < 8; ++i) {
            int ii = hf * 8 + i;
            float p = ev[ii] * inv;
            e_s[d2 * TE + ii * 64 + l] = p;
            eo[ii * 64 + l] = p;
        }
        __syncthreads();   // normalized p visible to all waves
    }

    // ---------------- Phase 3: context (pipelined, barrier-free) ------------
    const int h4 = l & 31, tsub = l >> 5;
    float4 acc4[DTILE];
    #pragma unroll
    for (int d = 0; d < DTILE; ++d) acc4[d] = make_float4(0.f, 0.f, 0.f, 0.f);

    auto p3c = [&](int tt, const float* buf) {
        float4 ep[DTILE];
        #pragma unroll
        for (int d = 0; d < DTILE; ++d)
            ep[d] = *(const float4*)&e_s[d * TE + tt * TTILE + w * 8 + tsub * 4];
        #pragma unroll
        for (int k = 0; k < 4; ++k) {
            float4 x = *(const float4*)&buf[(tsub * 4 + k) * HH + h4 * 4];
            float p0 = k == 0 ? ep[0].x : k == 1 ? ep[0].y : k == 2 ? ep[0].z : ep[0].w;
            float p1 = k == 0 ? ep[1].x : k == 1 ? ep[1].y : k == 2 ? ep[1].z : ep[1].w;
            float p2 = k == 0 ? ep[2].x : k == 1 ? ep[2].y : k == 2 ? ep[2].z : ep[2].w;
            float p3 = k == 0 ? ep[3].x : k == 1 ? ep[3].y : k == 2 ? ep[3].z : ep[3].w;
            acc4[0].x = fmaf(p0, x.x, acc4[0].x); acc4[0].y = fmaf(p0, x.y, acc4[0].y);
            acc4[0].z = fmaf(p0, x.z, acc4[0].z); acc4[0].w = fmaf(p0, x.w, acc4[0].w);
            acc4[1].x = fmaf(p1, x.x, acc4[1].x); acc4[1].y = fmaf(p1, x.y, acc4[1].y);
            acc4[1].z = fmaf(p1, x.z, acc4[1].z); acc4[1].w = fmaf(p1, x.w, acc4[1].w);
            acc4[2].x = fmaf(p2, x.x, acc4[2].x); acc4[2].y = fmaf(p2, x.y, acc4[2].y);
            acc4[2].z = fmaf(p2, x.z, acc4[2].z); acc4[2].w = fmaf(p2, x.w, acc4[2].w);
            acc4[3].x = fmaf(p3, x.x, acc4[3].x); acc4[3].y = fmaf(p3, x.y, acc4[3].y);
            acc4[3].z = fmaf(p3, x.z, acc4[3].z); acc4[3].w = fmaf(p3, x.w, acc4[3].w);
        }
    };

    #pragma unroll
    for (int i = 0; i < 4; ++i)                       // prologue: tile 0 -> buf0
        gload16_lds(enc_w + i * 256 + l * 4, slab + i * 256);

    for (int tt = 0; tt < 15; ++tt) {
        const float* src = enc_w + (size_t)(tt + 1) * TTILE * HH;
        float* nb = slab + ((tt + 1) & 1) * 1024;
        #pragma unroll
        for (int i = 0; i < 4; ++i)
            gload16_lds(src + i * 256 + l * 4, nb + i * 256);
        __builtin_amdgcn_s_waitcnt(0x0F74);           // vmcnt(4)
        p3c(tt, slab + (tt & 1) * 1024);
        __builtin_amdgcn_sched_barrier(0);
    }
    __builtin_amdgcn_s_waitcnt(0x0F70);               // vmcnt(0)
    p3c(15, slab + 1024);

    // Combine tsub halves; park partials in tile (now dead); tree-reduce.
    #pragma unroll
    for (int d = 0; d < DTILE; ++d) {
        acc4[d].x += __shfl_xor(acc4[d].x, 32);
        acc4[d].y += __shfl_xor(acc4[d].y, 32);
        acc4[d].z += __shfl_xor(acc4[d].z, 32);
        acc4[d].w += __shfl_xor(acc4[d].w, 32);
    }
    __syncthreads();   // all waves done READING tile before we overwrite it
    float* c_red = tile;   // 8 waves x DTILE x HH = 16 KB <= 64 KB
    if (tsub == 0) {
        #pragma unroll
        for (int d = 0; d < DTILE; ++d)
            *(float4*)&c_red[(w * DTILE + d) * HH + h4 * 4] = acc4[d];
    }
    __syncthreads();

    if (w < DTILE && l < 32) {
        float4 o = make_float4(0.f, 0.f, 0.f, 0.f);
        #pragma unroll
        for (int ww = 0; ww < 8; ++ww) {
            float4 p = *(const float4*)&c_red[(ww * DTILE + w) * HH + l * 4];
            o.x += p.x; o.y += p.y; o.z += p.z; o.w += p.w;
        }
        *(float4*)&c_out[((size_t)b * TD + d0 + w) * HH + l * 4] = o;
    }
}

// ---------------------------------------------------------------------------
extern "C" void kernel_launch(void* const* d_in, const int* in_sizes, int n_in,
                              void* d_out, int out_size, void* d_ws, size_t ws_size,
                              hipStream_t stream) {
    (void)in_sizes; (void)n_in; (void)out_size; (void)ws_size;

    const float* enc = (const float*)d_in[0];
    const float* dec = (const float*)d_in[1];
    const float* Wa  = (const float*)d_in[2];
    const float* Ua  = (const float*)d_in[3];
    const float* Va  = (const float*)d_in[4];

    float* c_out = (float*)d_out;
    float* e_out = (float*)d_out + BB * TD * HH;

    float* proj = (float*)d_ws;
    float* ta_p = proj;                  // tanh(W_s): [B*TE, H]
    float* tb_p = proj + BB * TE * HH;   // tanh(U_h): [B*TD, H]

    proj_gemm<<<192, 256, 0, stream>>>(enc, dec, Wa, Ua, proj);
    attn_fused<<<(BB * TD) / DTILE, 512, 0, stream>>>(enc, ta_p, tb_p, Va, c_out, e_out);
}

// Round 9
// 125.814 us; speedup vs baseline: 1.2922x; 1.0947x over previous
//
#include <hip/hip_runtime.h>

#define BB    4
#define TE    1024
#define TD    512
#define HH    128
#define DTILE 4
#define TTILE 64
#define LOG2E 1.4426950408889634f

// Accurate-enough tanh for the proj epilogue (786K elems, off the hot path).
__device__ __forceinline__ float tanh_eval(float x) {
    float e = __builtin_amdgcn_exp2f(2.0f * LOG2E * x);
    return 1.0f - 2.0f * __builtin_amdgcn_rcpf(e + 1.0f);
}

// Combined fraction over 4 elements: sum_i v_i*(A_i+B_i)/(1+A_i*B_i) = n/den
// (exact algebra; 21 full-rate ops, no transcendental).
__device__ __forceinline__ void quad_nd(float4 A, float4 B, float4 v,
                                        float& n, float& den) {
    float n0 = v.x * (A.x + B.x), d0 = fmaf(A.x, B.x, 1.0f);
    float n1 = v.y * (A.y + B.y), d1 = fmaf(A.y, B.y, 1.0f);
    float n2 = v.z * (A.z + B.z), d2 = fmaf(A.z, B.z, 1.0f);
    float n3 = v.w * (A.w + B.w), d3 = fmaf(A.w, B.w, 1.0f);
    float n01 = fmaf(n0, d1, n1 * d0), d01 = d0 * d1;
    float n23 = fmaf(n2, d3, n3 * d2), d23 = d2 * d3;
    n   = fmaf(n01, d23, n23 * d01);
    den = d01 * d23;
}

// ---------------------------------------------------------------------------
// Kernel 1: tiled projections; epilogue applies tanh (A = tanh(enc@W),
// B = tanh(dec@U)) so the energy kernel can use the addition theorem.
// ---------------------------------------------------------------------------
__global__ __launch_bounds__(256) void proj_gemm(
    const float* __restrict__ enc, const float* __restrict__ dec,
    const float* __restrict__ Wa,  const float* __restrict__ Ua,
    float* __restrict__ out)
{
    __shared__ float Xs[64 * 33];
    __shared__ float Ws[32 * 64];

    const int tid = threadIdx.x;
    const int rt = blockIdx.x >> 1, ch = blockIdx.x & 1;
    const int r0 = rt * 64, c0 = ch * 64;

    const float* X; const float* W; int rX0;
    if (r0 < BB * TE) { X = enc; W = Wa; rX0 = r0; }
    else              { X = dec; W = Ua; rX0 = r0 - BB * TE; }

    const int c4 = tid & 15;
    const int rg = tid >> 4;

    float4 a0 = {0,0,0,0}, a1 = a0, a2 = a0, a3 = a0;

    for (int kc = 0; kc < 4; ++kc) {
        #pragma unroll
        for (int i = 0; i < 2; ++i) {
            int idx = tid + i * 256;
            int r  = idx >> 3, k4 = idx & 7;
            *(float4*)&Xs[r * 33 + k4 * 4] =
                *(const float4*)&X[(rX0 + r) * HH + kc * 32 + k4 * 4];
            int kk = idx >> 4, cc = idx & 15;
            *(float4*)&Ws[kk * 64 + cc * 4] =
                *(const float4*)&W[(kc * 32 + kk) * HH + c0 + cc * 4];
        }
        __syncthreads();
        #pragma unroll 8
        for (int k = 0; k < 32; ++k) {
            float4 wv = *(const float4*)&Ws[k * 64 + c4 * 4];
            float x0 = Xs[(rg * 4 + 0) * 33 + k];
            float x1 = Xs[(rg * 4 + 1) * 33 + k];
            float x2 = Xs[(rg * 4 + 2) * 33 + k];
            float x3 = Xs[(rg * 4 + 3) * 33 + k];
            a0.x = fmaf(x0, wv.x, a0.x); a0.y = fmaf(x0, wv.y, a0.y);
            a0.z = fmaf(x0, wv.z, a0.z); a0.w = fmaf(x0, wv.w, a0.w);
            a1.x = fmaf(x1, wv.x, a1.x); a1.y = fmaf(x1, wv.y, a1.y);
            a1.z = fmaf(x1, wv.z, a1.z); a1.w = fmaf(x1, wv.w, a1.w);
            a2.x = fmaf(x2, wv.x, a2.x); a2.y = fmaf(x2, wv.y, a2.y);
            a2.z = fmaf(x2, wv.z, a2.z); a2.w = fmaf(x2, wv.w, a2.w);
            a3.x = fmaf(x3, wv.x, a3.x); a3.y = fmaf(x3, wv.y, a3.y);
            a3.z = fmaf(x3, wv.z, a3.z); a3.w = fmaf(x3, wv.w, a3.w);
        }
        __syncthreads();
    }

    float4 accs[4] = {a0, a1, a2, a3};
    #pragma unroll
    for (int j = 0; j < 4; ++j) {
        float4 o = accs[j];
        o.x = tanh_eval(o.x); o.y = tanh_eval(o.y);
        o.z = tanh_eval(o.z); o.w = tanh_eval(o.w);
        *(float4*)&out[(r0 + rg * 4 + j) * HH + c0 + c4 * 4] = o;
    }
}

// ---------------------------------------------------------------------------
// Kernel 2: fused energies -> softmax -> context. NO LDS tile staging:
// both phases stream L2-resident tiles directly into a 2-deep register
// pingpong (manually unrolled x2). Energies: tanh addition theorem with
// 8-way combined fractions (1 rcp / 8 elements). LDS only for e_s + c_red.
// ---------------------------------------------------------------------------
__global__ __launch_bounds__(512, 4) void attn_fused(
    const float* __restrict__ enc,    // [B, TE, H] raw
    const float* __restrict__ ta,     // [B*TE, H]  = tanh(W_s)
    const float* __restrict__ tb,     // [B*TD, H]  = tanh(U_h)
    const float* __restrict__ Va,     // [H]
    float* __restrict__ c_out,        // [B, TD, H]
    float* __restrict__ e_out)        // [B, TD, TE]
{
    __shared__ float e_s[DTILE * TE];       // 16 KB
    __shared__ float c_red[8 * DTILE * HH]; // 16 KB

    const int tid = threadIdx.x;
    const int l   = tid & 63;
    const int w   = tid >> 6;            // 0..7 (row-octet owner)
    const int b   = blockIdx.x >> 7;
    const int d0  = (blockIdx.x & 127) * DTILE;

    const int c16 = l & 15;              // h-chunk selector / reduce dim
    const int r4  = l >> 4;              // row within half-octet

    // Register fragments: 8 h-values per d (2 float4), resident (~32+8 regs).
    float4 B4[DTILE][2], v4[2];
    #pragma unroll
    for (int j = 0; j < 2; ++j) {
        v4[j] = *(const float4*)&Va[(j * 16 + c16) * 4];
        #pragma unroll
        for (int d = 0; d < DTILE; ++d)
            B4[d][j] = *(const float4*)&tb[((size_t)b * TD + d0 + d) * HH + (j * 16 + c16) * 4];
    }

    const float* ta_w  = ta  + ((size_t)b * TE + w * 8) * HH;
    const float* enc_w = enc + ((size_t)b * TE + w * 8) * HH;

    // ---------------- Phase 1: energies (register pingpong) ----------------
    {
        float4 A0[2][2], A1[2][2];   // [half][j] x 2 buffers

        auto loadA = [&](int tt, float4 (&A)[2][2]) {
            const float* base = ta_w + (size_t)tt * TTILE * HH;
            #pragma unroll
            for (int hf = 0; hf < 2; ++hf)
                #pragma unroll
                for (int j = 0; j < 2; ++j)
                    A[hf][j] = *(const float4*)&base[(hf * 4 + r4) * HH + (j * 16 + c16) * 4];
        };

        auto p1c = [&](int tt, float4 (&A)[2][2]) {
            #pragma unroll
            for (int hf = 0; hf < 2; ++hf) {
                #pragma unroll
                for (int d = 0; d < DTILE; ++d) {
                    float na, da, nb, db;
                    quad_nd(A[hf][0], B4[d][0], v4[0], na, da);
                    quad_nd(A[hf][1], B4[d][1], v4[1], nb, db);
                    float num = fmaf(na, db, nb * da);
                    float den = da * db;
                    float e = num * __builtin_amdgcn_rcpf(den);
                    e += __shfl_xor(e, 1);
                    e += __shfl_xor(e, 2);
                    e += __shfl_xor(e, 4);
                    e += __shfl_xor(e, 8);
                    if (c16 == 0)
                        e_s[d * TE + tt * TTILE + w * 8 + hf * 4 + r4] = e;
                }
            }
        };

        loadA(0, A0);
        #pragma unroll 1
        for (int tt = 0; tt < 14; tt += 2) {
            loadA(tt + 1, A1);
            p1c(tt, A0);
            loadA(tt + 2, A0);
            p1c(tt + 1, A1);
        }
        loadA(15, A1);
        p1c(14, A0);
        p1c(15, A1);
    }
    __syncthreads();   // all waves' raw energies visible

    // ---------------- Phase 2: softmax (d = w&3, two waves split halves) ----
    {
        const int d2 = w & 3, hf = w >> 2;
        float ev[16];
        float m = -3.0e38f;
        #pragma unroll
        for (int i = 0; i < 16; ++i) {
            ev[i] = e_s[d2 * TE + i * 64 + l];
            m = fmaxf(m, ev[i]);
        }
        #pragma unroll
        for (int off = 32; off; off >>= 1) m = fmaxf(m, __shfl_xor(m, off));
        float s = 0.f;
        #pragma unroll
        for (int i = 0; i < 16; ++i) {
            ev[i] = __builtin_amdgcn_exp2f((ev[i] - m) * LOG2E);
            s += ev[i];
        }
        #pragma unroll
        for (int off = 32; off; off >>= 1) s += __shfl_xor(s, off);
        float inv = __builtin_amdgcn_rcpf(s);

        __syncthreads();   // all raw-energy reads done before overwrite
        float* eo = e_out + ((size_t)b * TD + d0 + d2) * TE;
        #pragma unroll
        for (int i = 0; i < 8; ++i) {
            int ii = hf * 8 + i;
            float p = ev[ii] * inv;
            e_s[d2 * TE + ii * 64 + l] = p;
            eo[ii * 64 + l] = p;
        }
        __syncthreads();   // normalized p visible to all waves
    }

    // ---------------- Phase 3: context (register pingpong) ------------------
    const int h4 = l & 31, tsub = l >> 5;
    float4 acc4[DTILE];
    #pragma unroll
    for (int d = 0; d < DTILE; ++d) acc4[d] = make_float4(0.f, 0.f, 0.f, 0.f);

    {
        float4 X0[4], X1[4];

        auto loadX = [&](int tt, float4 (&X)[4]) {
            const float* base = enc_w + (size_t)tt * TTILE * HH;
            #pragma unroll
            for (int k = 0; k < 4; ++k)
                X[k] = *(const float4*)&base[(tsub * 4 + k) * HH + h4 * 4];
        };

        auto p3c = [&](int tt, float4 (&X)[4]) {
            float4 ep[DTILE];
            #pragma unroll
            for (int d = 0; d < DTILE; ++d)
                ep[d] = *(const float4*)&e_s[d * TE + tt * TTILE + w * 8 + tsub * 4];
            #pragma unroll
            for (int k = 0; k < 4; ++k) {
                float4 x = X[k];
                float p0 = k == 0 ? ep[0].x : k == 1 ? ep[0].y : k == 2 ? ep[0].z : ep[0].w;
                float p1 = k == 0 ? ep[1].x : k == 1 ? ep[1].y : k == 2 ? ep[1].z : ep[1].w;
                float p2 = k == 0 ? ep[2].x : k == 1 ? ep[2].y : k == 2 ? ep[2].z : ep[2].w;
                float p3 = k == 0 ? ep[3].x : k == 1 ? ep[3].y : k == 2 ? ep[3].z : ep[3].w;
                acc4[0].x = fmaf(p0, x.x, acc4[0].x); acc4[0].y = fmaf(p0, x.y, acc4[0].y);
                acc4[0].z = fmaf(p0, x.z, acc4[0].z); acc4[0].w = fmaf(p0, x.w, acc4[0].w);
                acc4[1].x = fmaf(p1, x.x, acc4[1].x); acc4[1].y = fmaf(p1, x.y, acc4[1].y);
                acc4[1].z = fmaf(p1, x.z, acc4[1].z); acc4[1].w = fmaf(p1, x.w, acc4[1].w);
                acc4[2].x = fmaf(p2, x.x, acc4[2].x); acc4[2].y = fmaf(p2, x.y, acc4[2].y);
                acc4[2].z = fmaf(p2, x.z, acc4[2].z); acc4[2].w = fmaf(p2, x.w, acc4[2].w);
                acc4[3].x = fmaf(p3, x.x, acc4[3].x); acc4[3].y = fmaf(p3, x.y, acc4[3].y);
                acc4[3].z = fmaf(p3, x.z, acc4[3].z); acc4[3].w = fmaf(p3, x.w, acc4[3].w);
            }
        };

        loadX(0, X0);
        #pragma unroll 1
        for (int tt = 0; tt < 14; tt += 2) {
            loadX(tt + 1, X1);
            p3c(tt, X0);
            loadX(tt + 2, X0);
            p3c(tt + 1, X1);
        }
        loadX(15, X1);
        p3c(14, X0);
        p3c(15, X1);
    }

    // Combine tsub halves; park per-wave partials; tree-reduce across waves.
    #pragma unroll
    for (int d = 0; d < DTILE; ++d) {
        acc4[d].x += __shfl_xor(acc4[d].x, 32);
        acc4[d].y += __shfl_xor(acc4[d].y, 32);
        acc4[d].z += __shfl_xor(acc4[d].z, 32);
        acc4[d].w += __shfl_xor(acc4[d].w, 32);
    }
    if (tsub == 0) {
        #pragma unroll
        for (int d = 0; d < DTILE; ++d)
            *(float4*)&c_red[(w * DTILE + d) * HH + h4 * 4] = acc4[d];
    }
    __syncthreads();

    if (w < DTILE && l < 32) {
        float4 o = make_float4(0.f, 0.f, 0.f, 0.f);
        #pragma unroll
        for (int ww = 0; ww < 8; ++ww) {
            float4 p = *(const float4*)&c_red[(ww * DTILE + w) * HH + l * 4];
            o.x += p.x; o.y += p.y; o.z += p.z; o.w += p.w;
        }
        *(float4*)&c_out[((size_t)b * TD + d0 + w) * HH + l * 4] = o;
    }
}

// ---------------------------------------------------------------------------
extern "C" void kernel_launch(void* const* d_in, const int* in_sizes, int n_in,
                              void* d_out, int out_size, void* d_ws, size_t ws_size,
                              hipStream_t stream) {
    (void)in_sizes; (void)n_in; (void)out_size; (void)ws_size;

    const float* enc = (const float*)d_in[0];
    const float* dec = (const float*)d_in[1];
    const float* Wa  = (const float*)d_in[2];
    const float* Ua  = (const float*)d_in[3];
    const float* Va  = (const float*)d_in[4];

    float* c_out = (float*)d_out;
    float* e_out = (float*)d_out + BB * TD * HH;

    float* proj = (float*)d_ws;
    float* ta_p = proj;                  // tanh(W_s): [B*TE, H]
    float* tb_p = proj + BB * TE * HH;   // tanh(U_h): [B*TD, H]

    proj_gemm<<<192, 256, 0, stream>>>(enc, dec, Wa, Ua, proj);
    attn_fused<<<(BB * TD) / DTILE, 512, 0, stream>>>(enc, ta_p, tb_p, Va, c_out, e_out);
}